// Round 12
// baseline (29.764 us; speedup 1.0000x reference)
//
#include <hip/hip_runtime.h>

#define IW 4096
#define IH 4096
#define OH 4094
#define OW 4094
#define CG 1024              // col-groups per row (4 cols each)
#define NWG 4096             // (1024 * 1024) / 256
#define XCHUNK 512           // NWG / 8

typedef float f32x4 __attribute__((ext_vector_type(4)));
typedef float f32x2 __attribute__((ext_vector_type(2)));

__global__ __launch_bounds__(256) void conv3x3_r4p(
    const float* __restrict__ in, const float* __restrict__ wgt,
    const float* __restrict__ bias, float* __restrict__ out) {

    // XCD-aware bijective swizzle (4096 % 8 == 0).
    int b   = blockIdx.x;
    int swz = (b & 7) * XCHUNK + (b >> 3);
    int idx = swz * 256 + (int)threadIdx.x;

    int cg   = idx & (CG - 1);
    int rg   = idx >> 10;          // uniform within a block
    int x    = cg << 2;            // output col start (multiple of 4)
    int row0 = rg << 2;            // output row start (even)

    float wv[9];
#pragma unroll
    for (int i = 0; i < 9; ++i) wv[i] = wgt[i];
    float bs = bias[0];

    int nr    = (row0 + 4 <= OH) ? 4 : (OH - row0);  // 4, or 2 at rg==1023 (uniform)
    int nload = nr + 2;                              // input rows needed

    // 6 input row-segments of 6 floats each; independent loads back-to-back.
    float r[6][6];
#pragma unroll
    for (int t = 0; t < 6; ++t) {
        if (t < nload) {
            const float* rp = in + (size_t)(row0 + t) * IW + x;
            float4 a = *reinterpret_cast<const float4*>(rp);   // 16B-aligned
            r[t][0] = a.x; r[t][1] = a.y; r[t][2] = a.z; r[t][3] = a.w;
            if (x + 5 < IW) {                                  // false only at x==4092
                float2 e = *reinterpret_cast<const float2*>(rp + 4);
                r[t][4] = e.x; r[t][5] = e.y;
            } else { r[t][4] = 0.f; r[t][5] = 0.f; }
        } else {
#pragma unroll
            for (int j = 0; j < 6; ++j) r[t][j] = 0.f;
        }
    }

    float acc[4][4];
#pragma unroll
    for (int i = 0; i < 4; ++i)
#pragma unroll
        for (int c = 0; c < 4; ++c) acc[i][c] = bs;

#pragma unroll
    for (int orow = 0; orow < 4; ++orow) {
#pragma unroll
        for (int kh = 0; kh < 3; ++kh) {
            int t = orow + kh;
            float w0 = wv[kh * 3 + 0], w1 = wv[kh * 3 + 1], w2 = wv[kh * 3 + 2];
#pragma unroll
            for (int c = 0; c < 4; ++c)
                acc[orow][c] += w0 * r[t][c] + w1 * r[t][c + 1] + w2 * r[t][c + 2];
        }
    }

    // Stores: SAME widths/addresses as R9, but PLAIN (cached) stores — the
    // single A/B variable this round. Even rows: aligned f32x4. Odd rows:
    // two adjacent f32x2 (merge in writeback L2).
    int nc = (x + 4 <= OW) ? 4 : (OW - x);           // 4, or 2 at x==4092
#pragma unroll
    for (int orow = 0; orow < 4; ++orow) {
        if (orow < nr) {
            float* op = out + (size_t)(row0 + orow) * OW + x;
            if (nc == 4) {
                if ((orow & 1) == 0) {
                    *reinterpret_cast<f32x4*>(op) =
                        f32x4{ acc[orow][0], acc[orow][1], acc[orow][2], acc[orow][3] };
                } else {
                    *reinterpret_cast<f32x2*>(op)     = f32x2{ acc[orow][0], acc[orow][1] };
                    *reinterpret_cast<f32x2*>(op + 2) = f32x2{ acc[orow][2], acc[orow][3] };
                }
            } else {
                *reinterpret_cast<f32x2*>(op) = f32x2{ acc[orow][0], acc[orow][1] };
            }
        }
    }
}

extern "C" void kernel_launch(void* const* d_in, const int* in_sizes, int n_in,
                              void* d_out, int out_size, void* d_ws, size_t ws_size,
                              hipStream_t stream) {
    const float* in   = (const float*)d_in[0];
    const float* wgt  = (const float*)d_in[1];
    const float* bias = (const float*)d_in[2];
    float* out        = (float*)d_out;

    conv3x3_r4p<<<NWG, 256, 0, stream>>>(in, wgt, bias, out);
}

// Round 13
// 28.123 us; speedup vs baseline: 1.0584x; 1.0584x over previous
//
#include <hip/hip_runtime.h>

#define IW 4096
#define OH 4094
#define OW 4094
#define CG 1024              // col-groups per row (4 cols each)
#define NWG 4096             // (1024 * 1024) / 256
#define XCHUNK 512           // NWG / 8

typedef float f32x4 __attribute__((ext_vector_type(4)));
typedef float f32x2 __attribute__((ext_vector_type(2)));

__global__ __launch_bounds__(256) void conv3x3_shfl(
    const float* __restrict__ in, const float* __restrict__ wgt,
    const float* __restrict__ bias, float* __restrict__ out) {

    // XCD-aware bijective swizzle (4096 % 8 == 0).
    int b    = blockIdx.x;
    int swz  = (b & 7) * XCHUNK + (b >> 3);
    int idx  = swz * 256 + (int)threadIdx.x;
    int lane = (int)threadIdx.x & 63;

    int cg   = idx & (CG - 1);     // consecutive cg per lane within a wave
    int rg   = idx >> 10;          // wave-uniform (block-uniform, in fact)
    int x    = cg << 2;            // output col start (multiple of 4)
    int row0 = rg << 2;            // output row start (even)

    float wv[9];
#pragma unroll
    for (int i = 0; i < 9; ++i) wv[i] = wgt[i];
    float bs = bias[0];

    int nr    = (row0 + 4 <= OH) ? 4 : (OH - row0);  // wave-uniform: 4, or 2 at rg==1023
    int nload = nr + 2;

    // Loads: ONE aligned f32x4 per row per lane; the 2 tail cols come from the
    // next lane via shfl_down. Only lane 63 does a real (guarded) f32x2 tail
    // load -> load lane-requests drop ~2x vs R9.
    float r[6][6];
#pragma unroll
    for (int t = 0; t < 6; ++t) {
        if (t < nload) {                                   // wave-uniform branch
            const float* rp = in + (size_t)(row0 + t) * IW + x;
            f32x4 a = *reinterpret_cast<const f32x4*>(rp); // 16B-aligned
            float e4 = 0.f, e5 = 0.f;
            if (lane == 63 && x + 5 < IW) {                // cg==1023 excluded by guard
                f32x2 e = *reinterpret_cast<const f32x2*>(rp + 4);
                e4 = e[0]; e5 = e[1];
            }
            float n0 = __shfl_down(a[0], 1);               // lane i <- lane i+1
            float n1 = __shfl_down(a[1], 1);
            if (lane == 63) { n0 = e4; n1 = e5; }
            r[t][0] = a[0]; r[t][1] = a[1]; r[t][2] = a[2]; r[t][3] = a[3];
            r[t][4] = n0;   r[t][5] = n1;
        } else {
#pragma unroll
            for (int j = 0; j < 6; ++j) r[t][j] = 0.f;
        }
    }

    float acc[4][4];
#pragma unroll
    for (int i = 0; i < 4; ++i)
#pragma unroll
        for (int c = 0; c < 4; ++c) acc[i][c] = bs;

#pragma unroll
    for (int orow = 0; orow < 4; ++orow) {
#pragma unroll
        for (int kh = 0; kh < 3; ++kh) {
            int t = orow + kh;
            float w0 = wv[kh * 3 + 0], w1 = wv[kh * 3 + 1], w2 = wv[kh * 3 + 2];
#pragma unroll
            for (int c = 0; c < 4; ++c)
                acc[orow][c] += w0 * r[t][c] + w1 * r[t][c + 1] + w2 * r[t][c + 2];
        }
    }

    // Stores (all NT). Even rows: aligned f32x4 as before. Odd rows: shift the
    // store window +2 cols so it's 16B-aligned ((2r+x+2)%4==0); lane i stores
    // {acc[2],acc[3],next-lane acc[0],acc[1]} via shfl_down. Wave edges patched
    // with single-lane f32x2 stores. Store lane-requests drop ~1.5x vs R9.
    int nc = (x + 4 <= OW) ? 4 : (OW - x);           // 4, or 2 at cg==1023 (lane 63)
#pragma unroll
    for (int orow = 0; orow < 4; ++orow) {
        if (orow < nr) {                              // wave-uniform branch
            float* op = out + (size_t)(row0 + orow) * OW + x;
            if ((orow & 1) == 0) {
                if (nc == 4) {
                    f32x4 v = { acc[orow][0], acc[orow][1], acc[orow][2], acc[orow][3] };
                    __builtin_nontemporal_store(v, reinterpret_cast<f32x4*>(op));
                } else {
                    f32x2 v = { acc[orow][0], acc[orow][1] };
                    __builtin_nontemporal_store(v, reinterpret_cast<f32x2*>(op));
                }
            } else {
                float na0 = __shfl_down(acc[orow][0], 1);
                float na1 = __shfl_down(acc[orow][1], 1);
                if (lane == 0) {                      // left-edge 2 cols of this wave
                    f32x2 v = { acc[orow][0], acc[orow][1] };
                    __builtin_nontemporal_store(v, reinterpret_cast<f32x2*>(op));
                }
                if (lane < 63) {                      // aligned full-width body
                    f32x4 v = { acc[orow][2], acc[orow][3], na0, na1 };
                    __builtin_nontemporal_store(v, reinterpret_cast<f32x4*>(op + 2));
                } else if (nc == 4) {                 // wave right edge (not image edge)
                    f32x2 v = { acc[orow][2], acc[orow][3] };
                    __builtin_nontemporal_store(v, reinterpret_cast<f32x2*>(op + 2));
                }
                // cg==1023 lane 63: its cols 4092/4093 were written by lane 62's
                // na0/na1; cols 4094/4095 don't exist -> store nothing.
            }
        }
    }
}

extern "C" void kernel_launch(void* const* d_in, const int* in_sizes, int n_in,
                              void* d_out, int out_size, void* d_ws, size_t ws_size,
                              hipStream_t stream) {
    const float* in   = (const float*)d_in[0];
    const float* wgt  = (const float*)d_in[1];
    const float* bias = (const float*)d_in[2];
    float* out        = (float*)d_out;

    conv3x3_shfl<<<NWG, 256, 0, stream>>>(in, wgt, bias, out);
}